// Round 13
// baseline (200.365 us; speedup 1.0000x reference)
//
#include <hip/hip_runtime.h>

#define DEVI static __device__ __forceinline__

constexpr int B_ = 2, C_ = 128, H_ = 128, W_ = 256;
constexpr int CG_ = 32, MD_ = 96;
constexpr int HW_ = H_ * W_;        // 32768
constexpr int CHW_ = C_ * HW_;      // 4194304
constexpr int TEN_ = B_ * CHW_;     // 8388608 elements per tensor
constexpr int P16_ = TEN_ / 2;      // u32 count of a bf16-paired tensor

typedef short bf16x8 __attribute__((ext_vector_type(8)));
typedef float f32x16 __attribute__((ext_vector_type(16)));
typedef unsigned short ushort_t;

// ---------------- bf16 helpers ----------------
DEVI ushort_t f2b(float f) {
  unsigned u = __float_as_uint(f);
  return (ushort_t)((u + 0x7fffu + ((u >> 16) & 1u)) >> 16);   // RNE bf16
}
DEVI unsigned pk2(float a, float b) {
  return (unsigned)f2b(a) | ((unsigned)f2b(b) << 16);
}
DEVI float blo(unsigned u) { return __uint_as_float(u << 16); }
DEVI float bhi(unsigned u) { return __uint_as_float(u & 0xffff0000u); }
DEVI float sum8(uint4 v) {
  return blo(v.x) + bhi(v.x) + blo(v.y) + bhi(v.y) +
         blo(v.z) + bhi(v.z) + blo(v.w) + bhi(v.w);
}
DEVI int xcd_remap(int hw) { return (hw & 7) * 128 + (hw >> 3); }     // 1024 blocks
DEVI int xcd_remap512(int hw) { return (hw & 7) * 64 + (hw >> 3); }   // 512 blocks

// ---------------- weight convert: Wb[o][k] bf16 ----------------
struct WbPack { const float* s[6]; ushort_t* d[6]; };

__global__ __launch_bounds__(256) void k_wb(WbPack p) {
  int m = blockIdx.y;
  int idx = blockIdx.x * 256 + threadIdx.x;
  p.d[m][idx] = f2b(p.s[m][idx]);
}

// ======== shared GEMM core (32x32x16 bf16, tile 64px x 128o) ========
// LDS Xs[px][64 u32 = 128ch bf16 pairs]; 16B cluster swizzle cl' = cl ^ (px&7).
DEVI void gemm_core(const unsigned* Xs, const ushort_t* Wb, int lane, int wid,
                    f32x16& acc0, f32x16& acc1) {
  int hi = lane >> 5, lr = lane & 31;
  bf16x8 wf[8];
  const ushort_t* wbase = Wb + (wid * 32 + lr) * 128 + hi * 8;
#pragma unroll
  for (int kk = 0; kk < 8; ++kk) wf[kk] = *(const bf16x8*)(wbase + kk * 16);
  int xsw = lr & 7;
#pragma unroll
  for (int kk = 0; kk < 8; ++kk) {
    int cl = 2 * kk + hi;
    bf16x8 x0 = *(const bf16x8*)&Xs[lr * 64 + ((cl ^ xsw) << 2)];
    bf16x8 x1 = *(const bf16x8*)&Xs[(32 + lr) * 64 + ((cl ^ xsw) << 2)];
    acc0 = __builtin_amdgcn_mfma_f32_32x32x16_bf16(wf[kk], x0, acc0, 0, 0, 0);
    acc1 = __builtin_amdgcn_mfma_f32_32x32x16_bf16(wf[kk], x1, acc1, 0, 0, 0);
  }
}

// ---------------- k_trans: dw3x3 + conv1x1 + bias + resid + LN -> bf16 pairs ----------------
// 2-row tile: block covers rows h0,h0+1 x 64 px. Staging loads 4 input rows per
// 2 outputs (vs 6). Per-element tap statement order identical to R12.
__global__ __launch_bounds__(256) void k_trans(
    const float* __restrict__ X0, const float* __restrict__ X1,
    const ushort_t* __restrict__ Wb,
    const float* __restrict__ dww, const float* __restrict__ dwb,
    const float* __restrict__ cb,
    const float* __restrict__ lnw0, const float* __restrict__ lnb0,
    const float* __restrict__ lnw1, const float* __restrict__ lnb1,
    unsigned* __restrict__ O0, unsigned* __restrict__ O1) {
  __shared__ __align__(16) unsigned Xs[2][64 * 64];
  __shared__ float red[640];
  int side = blockIdx.y;
  const float* X = side ? X1 : X0;
  const float* lnw = side ? lnw1 : lnw0;
  const float* lnb = side ? lnb1 : lnb0;
  unsigned* O = side ? O1 : O0;
  int bid = xcd_remap512(blockIdx.x);          // 512 blocks
  int b = bid >> 8, hp = (bid >> 2) & 63, w0 = (bid & 3) << 6;
  int h0 = hp * 2;
  int t = threadIdx.x;
  int lane = t & 63, wid = t >> 6, hi = lane >> 5, lr = lane & 31;

  int oct = t & 7, cg = t >> 3;
  int wb2 = w0 + oct * 8;
#pragma unroll
  for (int p = 0; p < 2; ++p) {        // channel pair p: channels 4cg+2p, 4cg+2p+1
    float accs[2][2][8];               // [out-row][cc][px]
#pragma unroll
    for (int cc = 0; cc < 2; ++cc) {
      int c = cg * 4 + p * 2 + cc;
      const float* Xp = X + (b * C_ + c) * HW_;
      const float* wp = dww + c * 9;
      float bb = dwb[c];
#pragma unroll
      for (int i = 0; i < 8; ++i) { accs[0][cc][i] = bb; accs[1][cc][i] = bb; }
#pragma unroll
      for (int r = 0; r < 4; ++r) {    // input rows h0-1 .. h0+2
        int hh = h0 - 1 + r;
        if (hh < 0 || hh >= H_) continue;
        const float* row = Xp + hh * W_;
        float4 a = *(const float4*)(row + wb2);
        float4 bq = *(const float4*)(row + wb2 + 4);
        float vm = (wb2 > 0) ? row[wb2 - 1] : 0.f;
        float vp = (wb2 + 8 < W_) ? row[wb2 + 8] : 0.f;
        float v10[10] = {vm, a.x, a.y, a.z, a.w, bq.x, bq.y, bq.z, bq.w, vp};
        if (r <= 2) {                  // out row h0, tap dy = r-1
          const float* wr = wp + r * 3;
          float tw0 = wr[0], tw1 = wr[1], tw2 = wr[2];
#pragma unroll
          for (int i = 0; i < 8; ++i) {
            accs[0][cc][i] += tw0 * v10[i];      // sequential v_fmac, R12 order
            accs[0][cc][i] += tw1 * v10[i + 1];
            accs[0][cc][i] += tw2 * v10[i + 2];
          }
        }
        if (r >= 1) {                  // out row h0+1, tap dy = r-2
          const float* wr = wp + (r - 1) * 3;
          float tw0 = wr[0], tw1 = wr[1], tw2 = wr[2];
#pragma unroll
          for (int i = 0; i < 8; ++i) {
            accs[1][cc][i] += tw0 * v10[i];
            accs[1][cc][i] += tw1 * v10[i + 1];
            accs[1][cc][i] += tw2 * v10[i + 2];
          }
        }
      }
    }
    int wic = (2 * cg + p) & 3;
    int clb = cg >> 1;
#pragma unroll
    for (int tr = 0; tr < 2; ++tr)
#pragma unroll
      for (int k = 0; k < 8; ++k) {
        int pxl = (k + oct) & 7;
        int px = oct * 8 + pxl;
        Xs[tr][px * 64 + (((clb ^ pxl) & 15) << 2) + wic] =
            pk2(accs[tr][0][pxl], accs[tr][1][pxl]);
      }
  }
  __syncthreads();

  // weight A-frags loaded once, reused for both rows
  bf16x8 wf[8];
  const ushort_t* wbase = Wb + (wid * 32 + lr) * 128 + hi * 8;
#pragma unroll
  for (int kk = 0; kk < 8; ++kk) wf[kk] = *(const bf16x8*)(wbase + kk * 16);
  int xsw = lr & 7;
  int obase = wid * 32 + 4 * hi;

#pragma unroll
  for (int tr = 0; tr < 2; ++tr) {
    if (tr) __syncthreads();           // protect red reuse across rows
    int h = h0 + tr;
    f32x16 acc0 = {}, acc1 = {};
#pragma unroll
    for (int kk = 0; kk < 8; ++kk) {
      int cl = 2 * kk + hi;
      bf16x8 x0 = *(const bf16x8*)&Xs[tr][lr * 64 + ((cl ^ xsw) << 2)];
      bf16x8 x1 = *(const bf16x8*)&Xs[tr][(32 + lr) * 64 + ((cl ^ xsw) << 2)];
      acc0 = __builtin_amdgcn_mfma_f32_32x32x16_bf16(wf[kk], x0, acc0, 0, 0, 0);
      acc1 = __builtin_amdgcn_mfma_f32_32x32x16_bf16(wf[kk], x1, acc1, 0, 0, 0);
    }
#pragma unroll
    for (int r = 0; r < 16; ++r) {
      int o = obase + (r & 3) + 8 * (r >> 2);
      float bb = cb[o];
      const float* rp = X + (b * C_ + o) * HW_ + h * W_ + w0;
      acc0[r] += bb + rp[lr];
      acc1[r] += bb + rp[32 + lr];
    }
    {
      float s0 = 0, s1 = 0, q0 = 0, q1 = 0;
#pragma unroll
      for (int r = 0; r < 16; ++r) {
        s0 += acc0[r]; q0 += acc0[r] * acc0[r];
        s1 += acc1[r]; q1 += acc1[r] * acc1[r];
      }
      s0 += __shfl_xor(s0, 32); q0 += __shfl_xor(q0, 32);
      s1 += __shfl_xor(s1, 32); q1 += __shfl_xor(q1, 32);
      if (hi == 0) {
        red[wid * 64 + lr] = s0;       red[wid * 64 + 32 + lr] = s1;
        red[256 + wid * 64 + lr] = q0; red[256 + wid * 64 + 32 + lr] = q1;
      }
      __syncthreads();
      if (t < 64) {
        float ss = red[t] + red[64 + t] + red[128 + t] + red[192 + t];
        float qq = red[256 + t] + red[320 + t] + red[384 + t] + red[448 + t];
        float mu = ss * (1.0f / 128.0f);
        float var = qq * (1.0f / 128.0f) - mu * mu;   // biased
        red[512 + t] = mu;
        red[576 + t] = rsqrtf(var + 1e-6f);
      }
      __syncthreads();
      float mu0 = red[512 + lr], rs0 = red[576 + lr];
      float mu1 = red[544 + lr], rs1 = red[608 + lr];
#pragma unroll
      for (int r = 0; r < 16; ++r) {
        int o = obase + (r & 3) + 8 * (r >> 2);
        float lw = lnw[o], lb2 = lnb[o];
        acc0[r] = lw * ((acc0[r] - mu0) * rs0) + lb2;
        acc1[r] = lw * ((acc1[r] - mu1) * rs1) + lb2;
      }
    }
#pragma unroll
    for (int r = 0; r < 16; r += 2) {
      int o = obase + (r & 3) + 8 * (r >> 2);
      unsigned* orow = O + (b * 64 + (o >> 1)) * HW_ + h * W_ + w0;
      orow[lr] = pk2(acc0[r], acc0[r + 1]);
      orow[32 + lr] = pk2(acc1[r], acc1[r + 1]);
    }
  }
}

// ---------------- k_qv: UNCHANGED from R9-R12 (verified) ----------------
__global__ __launch_bounds__(256) void k_qv(
    const unsigned* __restrict__ B0, const unsigned* __restrict__ B1,
    const float* __restrict__ X0, const float* __restrict__ X1,
    const ushort_t* __restrict__ WQ0, const ushort_t* __restrict__ WQ1,
    const ushort_t* __restrict__ WV0, const ushort_t* __restrict__ WV1,
    unsigned* __restrict__ Q0, unsigned* __restrict__ Q1,
    unsigned* __restrict__ V0, unsigned* __restrict__ V1) {
  __shared__ __align__(16) unsigned Xs[64 * 64];
  int ty = blockIdx.y;                // 0 QL, 1 QR, 2 VL, 3 VR
  int bid = xcd_remap(blockIdx.x);
  int b = bid >> 9, h = (bid >> 2) & 127, w0 = (bid & 3) << 6;
  int t = threadIdx.x;
  int lane = t & 63, wid = t >> 6, hi = lane >> 5, lr = lane & 31;
  const ushort_t* Wb = (ty == 0) ? WQ0 : (ty == 1) ? WQ1 : (ty == 2) ? WV0 : WV1;

  if (ty < 2) {
    const unsigned* S = ty ? B1 : B0;
#pragma unroll
    for (int uu = 0; uu < 4; ++uu) {
      int unit = uu * 256 + t;
      int c2u = unit >> 4, pxq = unit & 15;
      int wb2 = w0 + pxq * 4;
      int g = c2u >> 3;
      unsigned v[4];
      const unsigned* rowp = S + (b * 64 + c2u) * HW_ + h * W_;
      if (g >= 4) {
        uint4 a = *(const uint4*)(rowp + wb2);
        v[0] = a.x; v[1] = a.y; v[2] = a.z; v[3] = a.w;
      } else if (g >= 2) {
        int hh = h + (g == 2 ? 1 : -1);
        if (hh >= 0 && hh < H_) {
          uint4 a = *(const uint4*)(S + (b * 64 + c2u) * HW_ + hh * W_ + wb2);
          v[0] = a.x; v[1] = a.y; v[2] = a.z; v[3] = a.w;
        } else { v[0] = v[1] = v[2] = v[3] = 0u; }
      } else {
        int d = (g == 0) ? 1 : -1;
#pragma unroll
        for (int i = 0; i < 4; ++i) {
          int ww = wb2 + i + d;
          v[i] = (ww >= 0 && ww < W_) ? rowp[ww] : 0u;
        }
      }
#pragma unroll
      for (int i = 0; i < 4; ++i) {
        int px = pxq * 4 + i;
        Xs[px * 64 + (((c2u >> 2) ^ (px & 7)) << 2) + (c2u & 3)] = v[i];
      }
    }
  } else {
    const float* S = (ty == 2) ? X0 : X1;
    int ch8 = t >> 4, pxq = t & 15;
    int c0 = ch8 * 8, wb2 = w0 + pxq * 4;
    float vv[8][4];
#pragma unroll
    for (int cc = 0; cc < 8; ++cc) {
      int c = c0 + cc;
      int g = c >> 4;
      const float* rowp = S + (b * C_ + c) * HW_ + h * W_;
      if (g >= 4) {
        float4 a = *(const float4*)(rowp + wb2);
        vv[cc][0] = a.x; vv[cc][1] = a.y; vv[cc][2] = a.z; vv[cc][3] = a.w;
      } else if (g >= 2) {
        int hh = h + (g == 2 ? 1 : -1);
        if (hh >= 0 && hh < H_) {
          float4 a = *(const float4*)(S + (b * C_ + c) * HW_ + hh * W_ + wb2);
          vv[cc][0] = a.x; vv[cc][1] = a.y; vv[cc][2] = a.z; vv[cc][3] = a.w;
        } else { vv[cc][0] = vv[cc][1] = vv[cc][2] = vv[cc][3] = 0.f; }
      } else if (g == 0) {       // w+1 shift
        float4 a = *(const float4*)(rowp + wb2);
        float x4 = (wb2 + 4 < W_) ? rowp[wb2 + 4] : 0.f;
        vv[cc][0] = a.y; vv[cc][1] = a.z; vv[cc][2] = a.w; vv[cc][3] = x4;
      } else {                    // w-1 shift
        float4 a = *(const float4*)(rowp + wb2);
        float xm = (wb2 > 0) ? rowp[wb2 - 1] : 0.f;
        vv[cc][0] = xm; vv[cc][1] = a.x; vv[cc][2] = a.y; vv[cc][3] = a.z;
      }
    }
#pragma unroll
    for (int i = 0; i < 4; ++i) {
      int px = pxq * 4 + i;
      int cl = ch8 ^ (px & 7);
      *(uint4*)&Xs[px * 64 + cl * 4] =
          make_uint4(pk2(vv[0][i], vv[1][i]), pk2(vv[2][i], vv[3][i]),
                     pk2(vv[4][i], vv[5][i]), pk2(vv[6][i], vv[7][i]));
    }
  }
  __syncthreads();

  f32x16 acc0 = {}, acc1 = {};
  gemm_core(Xs, Wb, lane, wid, acc0, acc1);

  int obase = wid * 32 + 4 * hi;
  if (ty < 2) {
    unsigned* O = ty ? Q1 : Q0;
#pragma unroll
    for (int r = 0; r < 16; r += 2) {
      int o = obase + (r & 3) + 8 * (r >> 2);                 // even
      unsigned* orow = O + b * CHW_ + o * HW_ + h * W_ + w0;  // even-slot strided
      orow[lr] = pk2(acc0[r], acc0[r + 1]);
      orow[32 + lr] = pk2(acc1[r], acc1[r + 1]);
    }
  } else {
    unsigned* O = (ty == 2) ? V0 : V1;
#pragma unroll
    for (int r = 0; r < 16; r += 2) {
      int o = obase + (r & 3) + 8 * (r >> 2);                 // even
      unsigned* orow = O + (b * 64 + (o >> 1)) * HW_ + h * W_ + w0;
      orow[lr] = pk2(acc0[r], acc0[r + 1]);
      orow[32 + lr] = pk2(acc1[r], acc1[r + 1]);
    }
  }
}

// ============ MFMA attention: UNCHANGED from R12 (verified) ============
DEVI bf16x8 ldfrag(const unsigned* A, int r, int cl) {
  int clp = cl ^ ((r >> 1) & 3);
  uint4 v = *(const uint4*)(A + r * 16 + clp * 4);
  return __builtin_bit_cast(bf16x8, v);
}
DEVI bf16x8 vfrag(const unsigned* Vt, int c, int ktg, int hi) {
  int jc = 2 * ktg + hi;
  int jcp = jc ^ (c & 7);
  uint4 v = *(const uint4*)(Vt + c * 128 + jcp * 4);
  return __builtin_bit_cast(bf16x8, v);
}
DEVI void stageQ16(const unsigned* __restrict__ G, unsigned* A, int t) {
  unsigned r[16];
#pragma unroll
  for (int c2 = 0; c2 < 16; ++c2) r[c2] = G[(2 * c2) * HW_ + t];
  int sw = (t >> 1) & 3;
#pragma unroll
  for (int cl = 0; cl < 4; ++cl) {
    int clp = cl ^ sw;
    *(uint4*)(A + t * 16 + clp * 4) =
        make_uint4(r[cl * 4], r[cl * 4 + 1], r[cl * 4 + 2], r[cl * 4 + 3]);
  }
}
DEVI void stageVt_wr(const unsigned* vbuf, unsigned* Vt, int t) {
  ushort_t* V16 = (ushort_t*)Vt;
#pragma unroll
  for (int c2 = 0; c2 < 16; ++c2) {
    unsigned u = vbuf[c2];
#pragma unroll
    for (int e = 0; e < 2; ++e) {
      int c = 2 * c2 + e;
      int w16 = (c * 128 + (((t >> 3) ^ (c & 7)) << 2) + ((t >> 1) & 3)) * 2 + (t & 1);
      V16[w16] = (ushort_t)(e ? (u >> 16) : (u & 0xffffu));
    }
  }
}
DEVI void stageVt(const unsigned* __restrict__ G, unsigned* Vt, int t) {
  unsigned vbuf[16];
#pragma unroll
  for (int c2 = 0; c2 < 16; ++c2) vbuf[c2] = G[c2 * HW_ + t];
  stageVt_wr(vbuf, Vt, t);
}
DEVI void psv_comp(const unsigned* Vt, float* psv, int t) {
  int jt = t >> 5, c = t & 31;
  float s = 0.f;
#pragma unroll
  for (int q = 0; q < 4; ++q) {
    int jcp = (4 * jt + q) ^ (c & 7);
    s += sum8(*(const uint4*)(Vt + c * 128 + jcp * 4));
  }
  psv[jt * 32 + c] = s;
}

template <int DIR>
DEVI void attn_pass(const unsigned* Ql_, const unsigned* Qk_, const unsigned* Vt,
                    const float* psv, float* emr, unsigned* __restrict__ outG,
                    int wid, int lane) {
  int hi = lane >> 5, cq = lane & 31;
#pragma unroll
  for (int s = 0; s < 2; ++s) {
    int qt = 2 * wid + s;
    int q = qt * 32 + cq;
    int jt0 = DIR ? qt : (qt >= 3 ? qt - 3 : 0);
    int jt1 = DIR ? (qt <= 4 ? qt + 3 : 7) : qt;
    int nt = jt1 - jt0 + 1;                      // wave-uniform
    bf16x8 bq0 = ldfrag(Ql_, q, hi);
    bf16x8 bq1 = ldfrag(Ql_, q, hi + 2);
    f32x16 S[4];
#pragma unroll
    for (int ji = 0; ji < 4; ++ji) {
      if (ji < nt) {
        int jt = jt0 + ji;
        f32x16 d = {};
        d = __builtin_amdgcn_mfma_f32_32x32x16_bf16(
            ldfrag(Qk_, jt * 32 + cq, hi), bq0, d, 0, 0, 0);
        d = __builtin_amdgcn_mfma_f32_32x32x16_bf16(
            ldfrag(Qk_, jt * 32 + cq, hi + 2), bq1, d, 0, 0, 0);
        S[ji] = d;
      }
    }
    float m = 0.f;
#pragma unroll
    for (int ji = 0; ji < 4; ++ji) if (ji < nt) {
      int jb = (jt0 + ji) * 32 + 4 * hi;
#pragma unroll
      for (int r = 0; r < 16; ++r) {
        int j = jb + (r & 3) + 8 * (r >> 2);
        bool act = DIR ? (j >= q && j <= q + MD_) : (j <= q && j >= q - MD_);
        float v = act ? S[ji][r] : 0.f;
        S[ji][r] = v;
        m = fmaxf(m, v);
      }
    }
    m = fmaxf(m, __shfl_xor(m, 32));
    float em_ = __expf(-m);
    float lsum = 0.f;
#pragma unroll
    for (int ji = 0; ji < 4; ++ji) if (ji < nt) {
#pragma unroll
      for (int r = 0; r < 16; ++r) {
        float e = __expf(S[ji][r] - m);
        S[ji][r] = e;
        lsum += e;
      }
    }
    lsum += __shfl_xor(lsum, 32);
    lsum += (float)((8 - nt) * 32) * em_;
    float rl = 1.f / lsum;
    if (hi == 0) { emr[qt * 32 + cq] = em_; emr[256 + qt * 32 + cq] = rl; }
    f32x16 acc = {};
#pragma unroll
    for (int ji = 0; ji < 4; ++ji) if (ji < nt) {
      int jt = jt0 + ji;
      unsigned x[8], ox[8];
#pragma unroll
      for (int w2 = 0; w2 < 8; ++w2) x[w2] = pk2(S[ji][2 * w2], S[ji][2 * w2 + 1]);
#pragma unroll
      for (int w2 = 0; w2 < 8; ++w2) ox[w2] = __shfl_xor(x[w2], 32);
#pragma unroll
      for (int hf = 0; hf < 2; ++hf) {
        unsigned w0 = hi ? ox[4 * hf + 2] : x[4 * hf + 0];
        unsigned w1 = hi ? ox[4 * hf + 3] : x[4 * hf + 1];
        unsigned w2_ = hi ? x[4 * hf + 2] : ox[4 * hf + 0];
        unsigned w3 = hi ? x[4 * hf + 3] : ox[4 * hf + 1];
        uint4 aw = make_uint4(w0, w1, w2_, w3);
        acc = __builtin_amdgcn_mfma_f32_32x32x16_bf16(
            __builtin_bit_cast(bf16x8, aw), vfrag(Vt, cq, 2 * jt + hf, hi),
            acc, 0, 0, 0);
      }
    }
    float Rv = 0.f;
#pragma unroll
    for (int jt = 0; jt < 8; ++jt)
      if (jt < jt0 || jt > jt1) Rv += psv[jt * 32 + cq];
    // out: bf16 px-paired [c][HW/2]; rows qr0 (even), qr0+1 are IN-LANE
#pragma unroll
    for (int r = 0; r < 16; r += 2) {
      int qr0 = (r & 3) + 8 * (r >> 2) + 4 * hi;               // even
      float v0 = (acc[r] + emr[qt * 32 + qr0] * Rv) * emr[256 + qt * 32 + qr0];
      float v1 = (acc[r + 1] + emr[qt * 32 + qr0 + 1] * Rv) * emr[256 + qt * 32 + qr0 + 1];
      outG[cq * (HW_ / 2) + ((qt * 32 + qr0) >> 1)] = pk2(v0, v1);
    }
  }
}

__global__ __launch_bounds__(256) void k_attn(
    const unsigned* __restrict__ qL, const unsigned* __restrict__ qR,
    const unsigned* __restrict__ vL, const unsigned* __restrict__ vR,
    unsigned* __restrict__ wL, unsigned* __restrict__ wR) {
  __shared__ __align__(16) unsigned Ql[4096];
  __shared__ __align__(16) unsigned Qr[4096];
  __shared__ __align__(16) unsigned Vt[4096];
  __shared__ float psv[256];
  __shared__ float emr[512];
  int t = threadIdx.x;
  int bid = blockIdx.x;
  int b = bid >> 9, k4 = (bid >> 7) & 3, h = bid & 127;
  int qoff = b * CHW_ + (k4 * CG_) * HW_ + h * W_;             // even-slot strided base
  int voff = (b * 64 + k4 * 16) * HW_ + h * W_;                // compact pair base (V in)
  int woff = (b * C_ + k4 * CG_) * (HW_ / 2) + h * (W_ / 2);   // px-paired base (warp out)
  stageQ16(qL + qoff, Ql, t);
  stageQ16(qR + qoff, Qr, t);
  stageVt(vR + voff, Vt, t);
  __syncthreads();
  psv_comp(Vt, psv, t);
  __syncthreads();
  int wid = t >> 6, lane = t & 63;
  // T14: issue vL global loads NOW; latency hides under pass L.
  unsigned vbuf[16];
  {
    const unsigned* G = vL + voff;
#pragma unroll
    for (int c2 = 0; c2 < 16; ++c2) vbuf[c2] = G[c2 * HW_ + t];
  }
  attn_pass<0>(Ql, Qr, Vt, psv, emr, wL + woff, wid, lane);
  __syncthreads();
  stageVt_wr(vbuf, Vt, t);      // LDS-write half only
  __syncthreads();
  psv_comp(Vt, psv, t);
  __syncthreads();
  attn_pass<1>(Qr, Ql, Vt, psv, emr, wR + woff, wid, lane);
}

// ---------------- k_fin: UNCHANGED from R10-R12 (verified) ----------------
__global__ __launch_bounds__(256) void k_fin(
    const unsigned* __restrict__ W0, const unsigned* __restrict__ W1,
    const float* __restrict__ X0, const float* __restrict__ X1,
    const ushort_t* __restrict__ Wb,
    float* __restrict__ O0, float* __restrict__ O1) {
  __shared__ __align__(16) unsigned Xs[64 * 64];
  int side = blockIdx.y;
  const unsigned* Wsrc = side ? W1 : W0;
  const float* R = side ? X1 : X0;
  float* O = side ? O1 : O0;
  int bid = blockIdx.x;
  int b = bid >> 9, h = (bid >> 2) & 127, w0 = (bid & 3) << 6;
  int t = threadIdx.x;
  int lane = t & 63, wid = t >> 6, hi = lane >> 5, lr = lane & 31;
#pragma unroll
  for (int uu = 0; uu < 8; ++uu) {
    int unit = uu * 256 + t;
    int cp = unit >> 5;             // channel-pair 0..63
    int jp = unit & 31;             // px-pair 0..31
    const unsigned* base = Wsrc + h * (W_ / 2) + (w0 >> 1) + jp;
    unsigned lo = base[(b * C_ + 2 * cp) * (HW_ / 2)];       // ch 2cp:   px 2jp, 2jp+1
    unsigned hi2 = base[(b * C_ + 2 * cp + 1) * (HW_ / 2)];  // ch 2cp+1: px 2jp, 2jp+1
    unsigned w0p = (lo & 0xffffu) | (hi2 << 16);             // px 2jp
    unsigned w1p = (lo >> 16) | (hi2 & 0xffff0000u);         // px 2jp+1
    int px0 = 2 * jp, px1 = 2 * jp + 1;
    Xs[px0 * 64 + (((cp >> 2) ^ (px0 & 7)) << 2) + (cp & 3)] = w0p;
    Xs[px1 * 64 + (((cp >> 2) ^ (px1 & 7)) << 2) + (cp & 3)] = w1p;
  }
  __syncthreads();
  f32x16 acc0 = {}, acc1 = {};
  gemm_core(Xs, Wb, lane, wid, acc0, acc1);
  int obase = wid * 32 + 4 * hi;
#pragma unroll
  for (int r = 0; r < 16; ++r) {
    int o = obase + (r & 3) + 8 * (r >> 2);
    const float* rp = R + (b * C_ + o) * HW_ + h * W_ + w0;
    float* op = O + (b * C_ + o) * HW_ + h * W_ + w0;
    op[lr] = acc0[r] + rp[lr];
    op[32 + lr] = acc1[r] + rp[32 + lr];
  }
}

// ---------------- launch ----------------
extern "C" void kernel_launch(void* const* d_in, const int* in_sizes, int n_in,
                              void* d_out, int out_size, void* d_ws, size_t ws_size,
                              hipStream_t stream) {
  const float* xl0    = (const float*)d_in[0];
  const float* xr0    = (const float*)d_in[1];
  const float* ln_l_w = (const float*)d_in[2];
  const float* ln_l_b = (const float*)d_in[3];
  const float* ln_r_w = (const float*)d_in[4];
  const float* ln_r_b = (const float*)d_in[5];
  const float* feaL_w = (const float*)d_in[6];
  const float* feaR_w = (const float*)d_in[7];
  const float* to_l_w = (const float*)d_in[8];
  const float* to_r_w = (const float*)d_in[9];
  const float* td_w   = (const float*)d_in[10];
  const float* td_b   = (const float*)d_in[11];
  const float* tp_w   = (const float*)d_in[12];
  const float* tp_b   = (const float*)d_in[13];
  const float* out_w  = (const float*)d_in[14];

  float* o0 = (float*)d_out;                 // final left (Q scratch first)
  float* o1 = o0 + TEN_;                     // final right
  unsigned* qL = (unsigned*)d_out;           // even-slot strided pairs in o0 region
  unsigned* qR = qL + TEN_;                  // in o1 region
  unsigned* bL = (unsigned*)d_ws;            // x_left bf16 pairs; later warpL (px-paired)
  unsigned* bR = bL + P16_;                  // x_right; later warpR
  unsigned* vL = bR + P16_;                  // V bf16 pairs (compact)
  unsigned* vR = vL + P16_;
  ushort_t* wb = (ushort_t*)(vR + P16_);
  ushort_t* wb_feaL = wb + 0 * 16384;
  ushort_t* wb_feaR = wb + 1 * 16384;
  ushort_t* wb_tol  = wb + 2 * 16384;
  ushort_t* wb_tor  = wb + 3 * 16384;
  ushort_t* wb_tp   = wb + 4 * 16384;
  ushort_t* wb_out  = wb + 5 * 16384;

  WbPack pw;
  pw.s[0] = feaL_w; pw.s[1] = feaR_w; pw.s[2] = to_l_w;
  pw.s[3] = to_r_w; pw.s[4] = tp_w;   pw.s[5] = out_w;
  pw.d[0] = wb_feaL; pw.d[1] = wb_feaR; pw.d[2] = wb_tol;
  pw.d[3] = wb_tor;  pw.d[4] = wb_tp;   pw.d[5] = wb_out;
  k_wb<<<dim3(64, 6), 256, 0, stream>>>(pw);

  // transition (fused dw3x3, 2-row tile) + bias + resid + LN -> bf16
  k_trans<<<dim3(512, 2), 256, 0, stream>>>(
      xl0, xr0, wb_tp, td_w, td_b, tp_b,
      ln_l_w, ln_l_b, ln_r_w, ln_r_b, bL, bR);

  // Q (shifted x_left/right) and V (shifted inputs), vectorized staging
  k_qv<<<dim3(1024, 4), 256, 0, stream>>>(
      bL, bR, xl0, xr0, wb_tol, wb_tor, wb_feaL, wb_feaR,
      qL, qR, vL, vR);

  // MFMA attention (fused 2-pass, T14 vL prefetch) -> bf16 px-paired warp
  k_attn<<<1024, 256, 0, stream>>>(qL, qR, vL, vR, bL, bR);

  // final conv + residual -> f32 outputs (overwrites Q scratch in d_out)
  k_fin<<<dim3(1024, 2), 256, 0, stream>>>(
      bL, bR, xl0, xr0, wb_out, o0, o1);
}

// Round 14
// 188.585 us; speedup vs baseline: 1.0625x; 1.0625x over previous
//
#include <hip/hip_runtime.h>

#define DEVI static __device__ __forceinline__

constexpr int B_ = 2, C_ = 128, H_ = 128, W_ = 256;
constexpr int CG_ = 32, MD_ = 96;
constexpr int HW_ = H_ * W_;        // 32768
constexpr int CHW_ = C_ * HW_;      // 4194304
constexpr int TEN_ = B_ * CHW_;     // 8388608 elements per tensor
constexpr int P16_ = TEN_ / 2;      // u32 count of a bf16-paired tensor

typedef short bf16x8 __attribute__((ext_vector_type(8)));
typedef float f32x16 __attribute__((ext_vector_type(16)));
typedef unsigned short ushort_t;

// ---------------- bf16 helpers ----------------
DEVI ushort_t f2b(float f) {
  unsigned u = __float_as_uint(f);
  return (ushort_t)((u + 0x7fffu + ((u >> 16) & 1u)) >> 16);   // RNE bf16
}
DEVI unsigned pk2(float a, float b) {
  return (unsigned)f2b(a) | ((unsigned)f2b(b) << 16);
}
DEVI float blo(unsigned u) { return __uint_as_float(u << 16); }
DEVI float bhi(unsigned u) { return __uint_as_float(u & 0xffff0000u); }
DEVI float sum8(uint4 v) {
  return blo(v.x) + bhi(v.x) + blo(v.y) + bhi(v.y) +
         blo(v.z) + bhi(v.z) + blo(v.w) + bhi(v.w);
}
DEVI int xcd_remap(int hw) { return (hw & 7) * 128 + (hw >> 3); }   // bijective, 1024%8==0

// ---------------- weight convert: Wb[o][k] bf16 ----------------
struct WbPack { const float* s[6]; ushort_t* d[6]; };

__global__ __launch_bounds__(256) void k_wb(WbPack p) {
  int m = blockIdx.y;
  int idx = blockIdx.x * 256 + threadIdx.x;
  p.d[m][idx] = f2b(p.s[m][idx]);
}

// ======== shared GEMM core (32x32x16 bf16, tile 64px x 128o) ========
// LDS Xs[px][64 u32 = 128ch bf16 pairs]; 16B cluster swizzle cl' = cl ^ (px&7).
DEVI void gemm_core(const unsigned* Xs, const ushort_t* Wb, int lane, int wid,
                    f32x16& acc0, f32x16& acc1) {
  int hi = lane >> 5, lr = lane & 31;
  bf16x8 wf[8];
  const ushort_t* wbase = Wb + (wid * 32 + lr) * 128 + hi * 8;
#pragma unroll
  for (int kk = 0; kk < 8; ++kk) wf[kk] = *(const bf16x8*)(wbase + kk * 16);
  int xsw = lr & 7;
#pragma unroll
  for (int kk = 0; kk < 8; ++kk) {
    int cl = 2 * kk + hi;
    bf16x8 x0 = *(const bf16x8*)&Xs[lr * 64 + ((cl ^ xsw) << 2)];
    bf16x8 x1 = *(const bf16x8*)&Xs[(32 + lr) * 64 + ((cl ^ xsw) << 2)];
    acc0 = __builtin_amdgcn_mfma_f32_32x32x16_bf16(wf[kk], x0, acc0, 0, 0, 0);
    acc1 = __builtin_amdgcn_mfma_f32_32x32x16_bf16(wf[kk], x1, acc1, 0, 0, 0);
  }
}

// ---------------- k_trans: dw3x3 + conv1x1 + bias + resid + LN -> bf16 pairs ----------------
// R9 form (verified best): 1-row tile, split channel-pair staging, VGPR 64.
__global__ __launch_bounds__(256) void k_trans(
    const float* __restrict__ X0, const float* __restrict__ X1,
    const ushort_t* __restrict__ Wb,
    const float* __restrict__ dww, const float* __restrict__ dwb,
    const float* __restrict__ cb,
    const float* __restrict__ lnw0, const float* __restrict__ lnb0,
    const float* __restrict__ lnw1, const float* __restrict__ lnb1,
    unsigned* __restrict__ O0, unsigned* __restrict__ O1) {
  __shared__ __align__(16) unsigned Xs[64 * 64];
  __shared__ float red[640];
  int side = blockIdx.y;
  const float* X = side ? X1 : X0;
  const float* lnw = side ? lnw1 : lnw0;
  const float* lnb = side ? lnb1 : lnb0;
  unsigned* O = side ? O1 : O0;
  int bid = xcd_remap(blockIdx.x);
  int b = bid >> 9, h = (bid >> 2) & 127, w0 = (bid & 3) << 6;
  int t = threadIdx.x;
  int lane = t & 63, wid = t >> 6, hi = lane >> 5, lr = lane & 31;

  int oct = t & 7, cg = t >> 3;
  int wb2 = w0 + oct * 8;
#pragma unroll
  for (int p = 0; p < 2; ++p) {        // channel pair p: channels 4cg+2p, 4cg+2p+1
    float accs[2][8];
#pragma unroll
    for (int cc = 0; cc < 2; ++cc) {
      int c = cg * 4 + p * 2 + cc;
      const float* Xp = X + (b * C_ + c) * HW_;
      const float* wp = dww + c * 9;
      float bb = dwb[c];
#pragma unroll
      for (int i = 0; i < 8; ++i) accs[cc][i] = bb;
#pragma unroll
      for (int dy = -1; dy <= 1; ++dy) {
        int hh = h + dy;
        if (hh < 0 || hh >= H_) continue;
        const float* row = Xp + hh * W_;
        float4 a = *(const float4*)(row + wb2);
        float4 bq = *(const float4*)(row + wb2 + 4);
        float vm = (wb2 > 0) ? row[wb2 - 1] : 0.f;
        float vp = (wb2 + 8 < W_) ? row[wb2 + 8] : 0.f;
        float v10[10] = {vm, a.x, a.y, a.z, a.w, bq.x, bq.y, bq.z, bq.w, vp};
        const float* wr = wp + (dy + 1) * 3;
        float tw0 = wr[0], tw1 = wr[1], tw2 = wr[2];
#pragma unroll
        for (int i = 0; i < 8; ++i) {
          accs[cc][i] += tw0 * v10[i];       // sequential v_fmac, R8 order
          accs[cc][i] += tw1 * v10[i + 1];
          accs[cc][i] += tw2 * v10[i + 2];
        }
      }
    }
    int wic = (2 * cg + p) & 3;
    int clb = cg >> 1;
#pragma unroll
    for (int k = 0; k < 8; ++k) {
      int pxl = (k + oct) & 7;
      int px = oct * 8 + pxl;
      Xs[px * 64 + (((clb ^ pxl) & 15) << 2) + wic] = pk2(accs[0][pxl], accs[1][pxl]);
    }
  }
  __syncthreads();

  f32x16 acc0 = {}, acc1 = {};
  gemm_core(Xs, Wb, lane, wid, acc0, acc1);

  int obase = wid * 32 + 4 * hi;
#pragma unroll
  for (int r = 0; r < 16; ++r) {
    int o = obase + (r & 3) + 8 * (r >> 2);
    float bb = cb[o];
    const float* rp = X + (b * C_ + o) * HW_ + h * W_ + w0;
    acc0[r] += bb + rp[lr];
    acc1[r] += bb + rp[32 + lr];
  }
  {
    float s0 = 0, s1 = 0, q0 = 0, q1 = 0;
#pragma unroll
    for (int r = 0; r < 16; ++r) {
      s0 += acc0[r]; q0 += acc0[r] * acc0[r];
      s1 += acc1[r]; q1 += acc1[r] * acc1[r];
    }
    s0 += __shfl_xor(s0, 32); q0 += __shfl_xor(q0, 32);
    s1 += __shfl_xor(s1, 32); q1 += __shfl_xor(q1, 32);
    if (hi == 0) {
      red[wid * 64 + lr] = s0;       red[wid * 64 + 32 + lr] = s1;
      red[256 + wid * 64 + lr] = q0; red[256 + wid * 64 + 32 + lr] = q1;
    }
    __syncthreads();
    if (t < 64) {
      float ss = red[t] + red[64 + t] + red[128 + t] + red[192 + t];
      float qq = red[256 + t] + red[320 + t] + red[384 + t] + red[448 + t];
      float mu = ss * (1.0f / 128.0f);
      float var = qq * (1.0f / 128.0f) - mu * mu;   // biased
      red[512 + t] = mu;
      red[576 + t] = rsqrtf(var + 1e-6f);
    }
    __syncthreads();
    float mu0 = red[512 + lr], rs0 = red[576 + lr];
    float mu1 = red[544 + lr], rs1 = red[608 + lr];
#pragma unroll
    for (int r = 0; r < 16; ++r) {
      int o = obase + (r & 3) + 8 * (r >> 2);
      float lw = lnw[o], lb2 = lnb[o];
      acc0[r] = lw * ((acc0[r] - mu0) * rs0) + lb2;
      acc1[r] = lw * ((acc1[r] - mu1) * rs1) + lb2;
    }
  }
#pragma unroll
  for (int r = 0; r < 16; r += 2) {
    int o = obase + (r & 3) + 8 * (r >> 2);
    unsigned* orow = O + (b * 64 + (o >> 1)) * HW_ + h * W_ + w0;
    orow[lr] = pk2(acc0[r], acc0[r + 1]);
    orow[32 + lr] = pk2(acc1[r], acc1[r + 1]);
  }
}

// ---------------- k_qv: UNCHANGED from R9-R12 (verified) ----------------
__global__ __launch_bounds__(256) void k_qv(
    const unsigned* __restrict__ B0, const unsigned* __restrict__ B1,
    const float* __restrict__ X0, const float* __restrict__ X1,
    const ushort_t* __restrict__ WQ0, const ushort_t* __restrict__ WQ1,
    const ushort_t* __restrict__ WV0, const ushort_t* __restrict__ WV1,
    unsigned* __restrict__ Q0, unsigned* __restrict__ Q1,
    unsigned* __restrict__ V0, unsigned* __restrict__ V1) {
  __shared__ __align__(16) unsigned Xs[64 * 64];
  int ty = blockIdx.y;                // 0 QL, 1 QR, 2 VL, 3 VR
  int bid = xcd_remap(blockIdx.x);
  int b = bid >> 9, h = (bid >> 2) & 127, w0 = (bid & 3) << 6;
  int t = threadIdx.x;
  int lane = t & 63, wid = t >> 6, hi = lane >> 5, lr = lane & 31;
  const ushort_t* Wb = (ty == 0) ? WQ0 : (ty == 1) ? WQ1 : (ty == 2) ? WV0 : WV1;

  if (ty < 2) {
    const unsigned* S = ty ? B1 : B0;
#pragma unroll
    for (int uu = 0; uu < 4; ++uu) {
      int unit = uu * 256 + t;
      int c2u = unit >> 4, pxq = unit & 15;
      int wb2 = w0 + pxq * 4;
      int g = c2u >> 3;
      unsigned v[4];
      const unsigned* rowp = S + (b * 64 + c2u) * HW_ + h * W_;
      if (g >= 4) {
        uint4 a = *(const uint4*)(rowp + wb2);
        v[0] = a.x; v[1] = a.y; v[2] = a.z; v[3] = a.w;
      } else if (g >= 2) {
        int hh = h + (g == 2 ? 1 : -1);
        if (hh >= 0 && hh < H_) {
          uint4 a = *(const uint4*)(S + (b * 64 + c2u) * HW_ + hh * W_ + wb2);
          v[0] = a.x; v[1] = a.y; v[2] = a.z; v[3] = a.w;
        } else { v[0] = v[1] = v[2] = v[3] = 0u; }
      } else {
        int d = (g == 0) ? 1 : -1;
#pragma unroll
        for (int i = 0; i < 4; ++i) {
          int ww = wb2 + i + d;
          v[i] = (ww >= 0 && ww < W_) ? rowp[ww] : 0u;
        }
      }
#pragma unroll
      for (int i = 0; i < 4; ++i) {
        int px = pxq * 4 + i;
        Xs[px * 64 + (((c2u >> 2) ^ (px & 7)) << 2) + (c2u & 3)] = v[i];
      }
    }
  } else {
    const float* S = (ty == 2) ? X0 : X1;
    int ch8 = t >> 4, pxq = t & 15;
    int c0 = ch8 * 8, wb2 = w0 + pxq * 4;
    float vv[8][4];
#pragma unroll
    for (int cc = 0; cc < 8; ++cc) {
      int c = c0 + cc;
      int g = c >> 4;
      const float* rowp = S + (b * C_ + c) * HW_ + h * W_;
      if (g >= 4) {
        float4 a = *(const float4*)(rowp + wb2);
        vv[cc][0] = a.x; vv[cc][1] = a.y; vv[cc][2] = a.z; vv[cc][3] = a.w;
      } else if (g >= 2) {
        int hh = h + (g == 2 ? 1 : -1);
        if (hh >= 0 && hh < H_) {
          float4 a = *(const float4*)(S + (b * C_ + c) * HW_ + hh * W_ + wb2);
          vv[cc][0] = a.x; vv[cc][1] = a.y; vv[cc][2] = a.z; vv[cc][3] = a.w;
        } else { vv[cc][0] = vv[cc][1] = vv[cc][2] = vv[cc][3] = 0.f; }
      } else if (g == 0) {       // w+1 shift
        float4 a = *(const float4*)(rowp + wb2);
        float x4 = (wb2 + 4 < W_) ? rowp[wb2 + 4] : 0.f;
        vv[cc][0] = a.y; vv[cc][1] = a.z; vv[cc][2] = a.w; vv[cc][3] = x4;
      } else {                    // w-1 shift
        float4 a = *(const float4*)(rowp + wb2);
        float xm = (wb2 > 0) ? rowp[wb2 - 1] : 0.f;
        vv[cc][0] = xm; vv[cc][1] = a.x; vv[cc][2] = a.y; vv[cc][3] = a.z;
      }
    }
#pragma unroll
    for (int i = 0; i < 4; ++i) {
      int px = pxq * 4 + i;
      int cl = ch8 ^ (px & 7);
      *(uint4*)&Xs[px * 64 + cl * 4] =
          make_uint4(pk2(vv[0][i], vv[1][i]), pk2(vv[2][i], vv[3][i]),
                     pk2(vv[4][i], vv[5][i]), pk2(vv[6][i], vv[7][i]));
    }
  }
  __syncthreads();

  f32x16 acc0 = {}, acc1 = {};
  gemm_core(Xs, Wb, lane, wid, acc0, acc1);

  int obase = wid * 32 + 4 * hi;
  if (ty < 2) {
    unsigned* O = ty ? Q1 : Q0;
#pragma unroll
    for (int r = 0; r < 16; r += 2) {
      int o = obase + (r & 3) + 8 * (r >> 2);                 // even
      unsigned* orow = O + b * CHW_ + o * HW_ + h * W_ + w0;  // even-slot strided
      orow[lr] = pk2(acc0[r], acc0[r + 1]);
      orow[32 + lr] = pk2(acc1[r], acc1[r + 1]);
    }
  } else {
    unsigned* O = (ty == 2) ? V0 : V1;
#pragma unroll
    for (int r = 0; r < 16; r += 2) {
      int o = obase + (r & 3) + 8 * (r >> 2);                 // even
      unsigned* orow = O + (b * 64 + (o >> 1)) * HW_ + h * W_ + w0;
      orow[lr] = pk2(acc0[r], acc0[r + 1]);
      orow[32 + lr] = pk2(acc1[r], acc1[r + 1]);
    }
  }
}

// ============ MFMA attention (R10 fused; T14 vL prefetch) ============
DEVI bf16x8 ldfrag(const unsigned* A, int r, int cl) {
  int clp = cl ^ ((r >> 1) & 3);
  uint4 v = *(const uint4*)(A + r * 16 + clp * 4);
  return __builtin_bit_cast(bf16x8, v);
}
DEVI bf16x8 vfrag(const unsigned* Vt, int c, int ktg, int hi) {
  int jc = 2 * ktg + hi;
  int jcp = jc ^ (c & 7);
  uint4 v = *(const uint4*)(Vt + c * 128 + jcp * 4);
  return __builtin_bit_cast(bf16x8, v);
}
DEVI void stageQ16(const unsigned* __restrict__ G, unsigned* A, int t) {
  unsigned r[16];
#pragma unroll
  for (int c2 = 0; c2 < 16; ++c2) r[c2] = G[(2 * c2) * HW_ + t];
  int sw = (t >> 1) & 3;
#pragma unroll
  for (int cl = 0; cl < 4; ++cl) {
    int clp = cl ^ sw;
    *(uint4*)(A + t * 16 + clp * 4) =
        make_uint4(r[cl * 4], r[cl * 4 + 1], r[cl * 4 + 2], r[cl * 4 + 3]);
  }
}
// LDS-write half of stageVt, from pre-loaded registers
DEVI void stageVt_wr(const unsigned* vbuf, unsigned* Vt, int t) {
  ushort_t* V16 = (ushort_t*)Vt;
#pragma unroll
  for (int c2 = 0; c2 < 16; ++c2) {
    unsigned u = vbuf[c2];
#pragma unroll
    for (int e = 0; e < 2; ++e) {
      int c = 2 * c2 + e;
      int w16 = (c * 128 + (((t >> 3) ^ (c & 7)) << 2) + ((t >> 1) & 3)) * 2 + (t & 1);
      V16[w16] = (ushort_t)(e ? (u >> 16) : (u & 0xffffu));
    }
  }
}
DEVI void stageVt(const unsigned* __restrict__ G, unsigned* Vt, int t) {
  unsigned vbuf[16];
#pragma unroll
  for (int c2 = 0; c2 < 16; ++c2) vbuf[c2] = G[c2 * HW_ + t];
  stageVt_wr(vbuf, Vt, t);
}
DEVI void psv_comp(const unsigned* Vt, float* psv, int t) {
  int jt = t >> 5, c = t & 31;
  float s = 0.f;
#pragma unroll
  for (int q = 0; q < 4; ++q) {
    int jcp = (4 * jt + q) ^ (c & 7);
    s += sum8(*(const uint4*)(Vt + c * 128 + jcp * 4));
  }
  psv[jt * 32 + c] = s;
}

template <int DIR>
DEVI void attn_pass(const unsigned* Ql_, const unsigned* Qk_, const unsigned* Vt,
                    const float* psv, float* emr, unsigned* __restrict__ outG,
                    int wid, int lane) {
  int hi = lane >> 5, cq = lane & 31;
#pragma unroll
  for (int s = 0; s < 2; ++s) {
    int qt = 2 * wid + s;
    int q = qt * 32 + cq;
    int jt0 = DIR ? qt : (qt >= 3 ? qt - 3 : 0);
    int jt1 = DIR ? (qt <= 4 ? qt + 3 : 7) : qt;
    int nt = jt1 - jt0 + 1;                      // wave-uniform
    bf16x8 bq0 = ldfrag(Ql_, q, hi);
    bf16x8 bq1 = ldfrag(Ql_, q, hi + 2);
    f32x16 S[4];
#pragma unroll
    for (int ji = 0; ji < 4; ++ji) {
      if (ji < nt) {
        int jt = jt0 + ji;
        f32x16 d = {};
        d = __builtin_amdgcn_mfma_f32_32x32x16_bf16(
            ldfrag(Qk_, jt * 32 + cq, hi), bq0, d, 0, 0, 0);
        d = __builtin_amdgcn_mfma_f32_32x32x16_bf16(
            ldfrag(Qk_, jt * 32 + cq, hi + 2), bq1, d, 0, 0, 0);
        S[ji] = d;
      }
    }
    float m = 0.f;
#pragma unroll
    for (int ji = 0; ji < 4; ++ji) if (ji < nt) {
      int jb = (jt0 + ji) * 32 + 4 * hi;
#pragma unroll
      for (int r = 0; r < 16; ++r) {
        int j = jb + (r & 3) + 8 * (r >> 2);
        bool act = DIR ? (j >= q && j <= q + MD_) : (j <= q && j >= q - MD_);
        float v = act ? S[ji][r] : 0.f;
        S[ji][r] = v;
        m = fmaxf(m, v);
      }
    }
    m = fmaxf(m, __shfl_xor(m, 32));
    float em_ = __expf(-m);
    float lsum = 0.f;
#pragma unroll
    for (int ji = 0; ji < 4; ++ji) if (ji < nt) {
#pragma unroll
      for (int r = 0; r < 16; ++r) {
        float e = __expf(S[ji][r] - m);
        S[ji][r] = e;
        lsum += e;
      }
    }
    lsum += __shfl_xor(lsum, 32);
    lsum += (float)((8 - nt) * 32) * em_;
    float rl = 1.f / lsum;
    if (hi == 0) { emr[qt * 32 + cq] = em_; emr[256 + qt * 32 + cq] = rl; }
    f32x16 acc = {};
#pragma unroll
    for (int ji = 0; ji < 4; ++ji) if (ji < nt) {
      int jt = jt0 + ji;
      unsigned x[8], ox[8];
#pragma unroll
      for (int w2 = 0; w2 < 8; ++w2) x[w2] = pk2(S[ji][2 * w2], S[ji][2 * w2 + 1]);
#pragma unroll
      for (int w2 = 0; w2 < 8; ++w2) ox[w2] = __shfl_xor(x[w2], 32);
#pragma unroll
      for (int hf = 0; hf < 2; ++hf) {
        unsigned w0 = hi ? ox[4 * hf + 2] : x[4 * hf + 0];
        unsigned w1 = hi ? ox[4 * hf + 3] : x[4 * hf + 1];
        unsigned w2_ = hi ? x[4 * hf + 2] : ox[4 * hf + 0];
        unsigned w3 = hi ? x[4 * hf + 3] : ox[4 * hf + 1];
        uint4 aw = make_uint4(w0, w1, w2_, w3);
        acc = __builtin_amdgcn_mfma_f32_32x32x16_bf16(
            __builtin_bit_cast(bf16x8, aw), vfrag(Vt, cq, 2 * jt + hf, hi),
            acc, 0, 0, 0);
      }
    }
    float Rv = 0.f;
#pragma unroll
    for (int jt = 0; jt < 8; ++jt)
      if (jt < jt0 || jt > jt1) Rv += psv[jt * 32 + cq];
    // out: bf16 px-paired [c][HW/2]; rows qr0 (even), qr0+1 are IN-LANE
#pragma unroll
    for (int r = 0; r < 16; r += 2) {
      int qr0 = (r & 3) + 8 * (r >> 2) + 4 * hi;               // even
      float v0 = (acc[r] + emr[qt * 32 + qr0] * Rv) * emr[256 + qt * 32 + qr0];
      float v1 = (acc[r + 1] + emr[qt * 32 + qr0 + 1] * Rv) * emr[256 + qt * 32 + qr0 + 1];
      outG[cq * (HW_ / 2) + ((qt * 32 + qr0) >> 1)] = pk2(v0, v1);
    }
  }
}

__global__ __launch_bounds__(256) void k_attn(
    const unsigned* __restrict__ qL, const unsigned* __restrict__ qR,
    const unsigned* __restrict__ vL, const unsigned* __restrict__ vR,
    unsigned* __restrict__ wL, unsigned* __restrict__ wR) {
  __shared__ __align__(16) unsigned Ql[4096];
  __shared__ __align__(16) unsigned Qr[4096];
  __shared__ __align__(16) unsigned Vt[4096];
  __shared__ float psv[256];
  __shared__ float emr[512];
  int t = threadIdx.x;
  int bid = blockIdx.x;
  int b = bid >> 9, k4 = (bid >> 7) & 3, h = bid & 127;
  int qoff = b * CHW_ + (k4 * CG_) * HW_ + h * W_;             // even-slot strided base
  int voff = (b * 64 + k4 * 16) * HW_ + h * W_;                // compact pair base (V in)
  int woff = (b * C_ + k4 * CG_) * (HW_ / 2) + h * (W_ / 2);   // px-paired base (warp out)
  stageQ16(qL + qoff, Ql, t);
  stageQ16(qR + qoff, Qr, t);
  stageVt(vR + voff, Vt, t);
  __syncthreads();
  psv_comp(Vt, psv, t);
  __syncthreads();
  int wid = t >> 6, lane = t & 63;
  // T14: issue vL global loads NOW; latency hides under pass L.
  unsigned vbuf[16];
  {
    const unsigned* G = vL + voff;
#pragma unroll
    for (int c2 = 0; c2 < 16; ++c2) vbuf[c2] = G[c2 * HW_ + t];
  }
  attn_pass<0>(Ql, Qr, Vt, psv, emr, wL + woff, wid, lane);
  __syncthreads();
  stageVt_wr(vbuf, Vt, t);      // LDS-write half only
  __syncthreads();
  psv_comp(Vt, psv, t);
  __syncthreads();
  attn_pass<1>(Qr, Ql, Vt, psv, emr, wR + woff, wid, lane);
}

// ---------------- k_fin: final conv + residual -> f32 out (px-paired bf16 warp in) ----------------
__global__ __launch_bounds__(256) void k_fin(
    const unsigned* __restrict__ W0, const unsigned* __restrict__ W1,
    const float* __restrict__ X0, const float* __restrict__ X1,
    const ushort_t* __restrict__ Wb,
    float* __restrict__ O0, float* __restrict__ O1) {
  __shared__ __align__(16) unsigned Xs[64 * 64];
  int side = blockIdx.y;
  const unsigned* Wsrc = side ? W1 : W0;
  const float* R = side ? X1 : X0;
  float* O = side ? O1 : O0;
  int bid = blockIdx.x;
  int b = bid >> 9, h = (bid >> 2) & 127, w0 = (bid & 3) << 6;
  int t = threadIdx.x;
  int lane = t & 63, wid = t >> 6, hi = lane >> 5, lr = lane & 31;
#pragma unroll
  for (int uu = 0; uu < 8; ++uu) {
    int unit = uu * 256 + t;
    int cp = unit >> 5;             // channel-pair 0..63
    int jp = unit & 31;             // px-pair 0..31
    const unsigned* base = Wsrc + h * (W_ / 2) + (w0 >> 1) + jp;
    unsigned lo = base[(b * C_ + 2 * cp) * (HW_ / 2)];       // ch 2cp:   px 2jp, 2jp+1
    unsigned hi2 = base[(b * C_ + 2 * cp + 1) * (HW_ / 2)];  // ch 2cp+1: px 2jp, 2jp+1
    unsigned w0p = (lo & 0xffffu) | (hi2 << 16);             // px 2jp
    unsigned w1p = (lo >> 16) | (hi2 & 0xffff0000u);         // px 2jp+1
    int px0 = 2 * jp, px1 = 2 * jp + 1;
    Xs[px0 * 64 + (((cp >> 2) ^ (px0 & 7)) << 2) + (cp & 3)] = w0p;
    Xs[px1 * 64 + (((cp >> 2) ^ (px1 & 7)) << 2) + (cp & 3)] = w1p;
  }
  __syncthreads();
  f32x16 acc0 = {}, acc1 = {};
  gemm_core(Xs, Wb, lane, wid, acc0, acc1);
  int obase = wid * 32 + 4 * hi;
#pragma unroll
  for (int r = 0; r < 16; ++r) {
    int o = obase + (r & 3) + 8 * (r >> 2);
    const float* rp = R + (b * C_ + o) * HW_ + h * W_ + w0;
    float* op = O + (b * C_ + o) * HW_ + h * W_ + w0;
    op[lr] = acc0[r] + rp[lr];
    op[32 + lr] = acc1[r] + rp[32 + lr];
  }
}

// ---------------- launch ----------------
extern "C" void kernel_launch(void* const* d_in, const int* in_sizes, int n_in,
                              void* d_out, int out_size, void* d_ws, size_t ws_size,
                              hipStream_t stream) {
  const float* xl0    = (const float*)d_in[0];
  const float* xr0    = (const float*)d_in[1];
  const float* ln_l_w = (const float*)d_in[2];
  const float* ln_l_b = (const float*)d_in[3];
  const float* ln_r_w = (const float*)d_in[4];
  const float* ln_r_b = (const float*)d_in[5];
  const float* feaL_w = (const float*)d_in[6];
  const float* feaR_w = (const float*)d_in[7];
  const float* to_l_w = (const float*)d_in[8];
  const float* to_r_w = (const float*)d_in[9];
  const float* td_w   = (const float*)d_in[10];
  const float* td_b   = (const float*)d_in[11];
  const float* tp_w   = (const float*)d_in[12];
  const float* tp_b   = (const float*)d_in[13];
  const float* out_w  = (const float*)d_in[14];

  float* o0 = (float*)d_out;                 // final left (Q scratch first)
  float* o1 = o0 + TEN_;                     // final right
  unsigned* qL = (unsigned*)d_out;           // even-slot strided pairs in o0 region
  unsigned* qR = qL + TEN_;                  // in o1 region
  unsigned* bL = (unsigned*)d_ws;            // x_left bf16 pairs; later warpL (px-paired)
  unsigned* bR = bL + P16_;                  // x_right; later warpR
  unsigned* vL = bR + P16_;                  // V bf16 pairs (compact)
  unsigned* vR = vL + P16_;
  ushort_t* wb = (ushort_t*)(vR + P16_);
  ushort_t* wb_feaL = wb + 0 * 16384;
  ushort_t* wb_feaR = wb + 1 * 16384;
  ushort_t* wb_tol  = wb + 2 * 16384;
  ushort_t* wb_tor  = wb + 3 * 16384;
  ushort_t* wb_tp   = wb + 4 * 16384;
  ushort_t* wb_out  = wb + 5 * 16384;

  WbPack pw;
  pw.s[0] = feaL_w; pw.s[1] = feaR_w; pw.s[2] = to_l_w;
  pw.s[3] = to_r_w; pw.s[4] = tp_w;   pw.s[5] = out_w;
  pw.d[0] = wb_feaL; pw.d[1] = wb_feaR; pw.d[2] = wb_tol;
  pw.d[3] = wb_tor;  pw.d[4] = wb_tp;   pw.d[5] = wb_out;
  k_wb<<<dim3(64, 6), 256, 0, stream>>>(pw);

  // transition (fused dw3x3) + bias + resid + LN -> bf16 x_left/x_right
  k_trans<<<dim3(1024, 2), 256, 0, stream>>>(
      xl0, xr0, wb_tp, td_w, td_b, tp_b,
      ln_l_w, ln_l_b, ln_r_w, ln_r_b, bL, bR);

  // Q (shifted x_left/right) and V (shifted inputs), vectorized staging
  k_qv<<<dim3(1024, 4), 256, 0, stream>>>(
      bL, bR, xl0, xr0, wb_tol, wb_tor, wb_feaL, wb_feaR,
      qL, qR, vL, vR);

  // MFMA attention (fused 2-pass, T14 vL prefetch) -> bf16 px-paired warp
  k_attn<<<1024, 256, 0, stream>>>(qL, qR, vL, vR, bL, bR);

  // final conv + residual -> f32 outputs (overwrites Q scratch in d_out)
  k_fin<<<dim3(1024, 2), 256, 0, stream>>>(
      bL, bR, xl0, xr0, wb_out, o0, o1);
}

// Round 15
// 180.145 us; speedup vs baseline: 1.1122x; 1.0469x over previous
//
#include <hip/hip_runtime.h>

#define DEVI static __device__ __forceinline__

constexpr int B_ = 2, C_ = 128, H_ = 128, W_ = 256;
constexpr int CG_ = 32, MD_ = 96;
constexpr int HW_ = H_ * W_;        // 32768
constexpr int CHW_ = C_ * HW_;      // 4194304
constexpr int TEN_ = B_ * CHW_;     // 8388608 elements per tensor
constexpr int P16_ = TEN_ / 2;      // u32 count of a bf16-paired tensor

typedef short bf16x8 __attribute__((ext_vector_type(8)));
typedef float f32x16 __attribute__((ext_vector_type(16)));
typedef unsigned short ushort_t;

// ---------------- bf16 helpers ----------------
DEVI ushort_t f2b(float f) {
  unsigned u = __float_as_uint(f);
  return (ushort_t)((u + 0x7fffu + ((u >> 16) & 1u)) >> 16);   // RNE bf16
}
DEVI unsigned pk2(float a, float b) {
  return (unsigned)f2b(a) | ((unsigned)f2b(b) << 16);
}
DEVI float blo(unsigned u) { return __uint_as_float(u << 16); }
DEVI float bhi(unsigned u) { return __uint_as_float(u & 0xffff0000u); }
DEVI float sum8(uint4 v) {
  return blo(v.x) + bhi(v.x) + blo(v.y) + bhi(v.y) +
         blo(v.z) + bhi(v.z) + blo(v.w) + bhi(v.w);
}
DEVI int xcd_remap(int hw) { return (hw & 7) * 128 + (hw >> 3); }   // bijective, 1024%8==0

// ---------------- weight convert: Wb[o][k] bf16 ----------------
struct WbPack { const float* s[6]; ushort_t* d[6]; };

__global__ __launch_bounds__(256) void k_wb(WbPack p) {
  int m = blockIdx.y;
  int idx = blockIdx.x * 256 + threadIdx.x;
  p.d[m][idx] = f2b(p.s[m][idx]);
}

// ======== shared GEMM core (32x32x16 bf16, tile 64px x 128o) ========
// LDS Xs[px][64 u32 = 128ch bf16 pairs]; 16B cluster swizzle cl' = cl ^ (px&7).
DEVI void gemm_core(const unsigned* Xs, const ushort_t* Wb, int lane, int wid,
                    f32x16& acc0, f32x16& acc1) {
  int hi = lane >> 5, lr = lane & 31;
  bf16x8 wf[8];
  const ushort_t* wbase = Wb + (wid * 32 + lr) * 128 + hi * 8;
#pragma unroll
  for (int kk = 0; kk < 8; ++kk) wf[kk] = *(const bf16x8*)(wbase + kk * 16);
  int xsw = lr & 7;
#pragma unroll
  for (int kk = 0; kk < 8; ++kk) {
    int cl = 2 * kk + hi;
    bf16x8 x0 = *(const bf16x8*)&Xs[lr * 64 + ((cl ^ xsw) << 2)];
    bf16x8 x1 = *(const bf16x8*)&Xs[(32 + lr) * 64 + ((cl ^ xsw) << 2)];
    acc0 = __builtin_amdgcn_mfma_f32_32x32x16_bf16(wf[kk], x0, acc0, 0, 0, 0);
    acc1 = __builtin_amdgcn_mfma_f32_32x32x16_bf16(wf[kk], x1, acc1, 0, 0, 0);
  }
}

// ---------------- k_tv: {transL, transR, VL, VR} in one dispatch ----------------
// ty = blockIdx.y: 0,1 -> transition (fused dw3x3 + conv + bias + resid + LN),
//                  2,3 -> V projection (shifted f32 input). Both paths verbatim
//                  from verified R14 kernels; independent write-sets.
__global__ __launch_bounds__(256) void k_tv(
    const float* __restrict__ X0, const float* __restrict__ X1,
    const ushort_t* __restrict__ Wtp,
    const ushort_t* __restrict__ WV0, const ushort_t* __restrict__ WV1,
    const float* __restrict__ dww, const float* __restrict__ dwb,
    const float* __restrict__ cb,
    const float* __restrict__ lnw0, const float* __restrict__ lnb0,
    const float* __restrict__ lnw1, const float* __restrict__ lnb1,
    unsigned* __restrict__ O0, unsigned* __restrict__ O1,
    unsigned* __restrict__ V0, unsigned* __restrict__ V1) {
  __shared__ __align__(16) unsigned Xs[64 * 64];
  __shared__ float red[640];
  int ty = blockIdx.y;
  int bid = xcd_remap(blockIdx.x);
  int b = bid >> 9, h = (bid >> 2) & 127, w0 = (bid & 3) << 6;
  int t = threadIdx.x;
  int lane = t & 63, wid = t >> 6, hi = lane >> 5, lr = lane & 31;

  if (ty < 2) {
    // ======== transition path (R14 k_trans verbatim) ========
    int side = ty;
    const float* X = side ? X1 : X0;
    const float* lnw = side ? lnw1 : lnw0;
    const float* lnb = side ? lnb1 : lnb0;
    unsigned* O = side ? O1 : O0;

    int oct = t & 7, cg = t >> 3;
    int wb2 = w0 + oct * 8;
#pragma unroll
    for (int p = 0; p < 2; ++p) {      // channel pair p: channels 4cg+2p, 4cg+2p+1
      float accs[2][8];
#pragma unroll
      for (int cc = 0; cc < 2; ++cc) {
        int c = cg * 4 + p * 2 + cc;
        const float* Xp = X + (b * C_ + c) * HW_;
        const float* wp = dww + c * 9;
        float bb = dwb[c];
#pragma unroll
        for (int i = 0; i < 8; ++i) accs[cc][i] = bb;
#pragma unroll
        for (int dy = -1; dy <= 1; ++dy) {
          int hh = h + dy;
          if (hh < 0 || hh >= H_) continue;
          const float* row = Xp + hh * W_;
          float4 a = *(const float4*)(row + wb2);
          float4 bq = *(const float4*)(row + wb2 + 4);
          float vm = (wb2 > 0) ? row[wb2 - 1] : 0.f;
          float vp = (wb2 + 8 < W_) ? row[wb2 + 8] : 0.f;
          float v10[10] = {vm, a.x, a.y, a.z, a.w, bq.x, bq.y, bq.z, bq.w, vp};
          const float* wr = wp + (dy + 1) * 3;
          float tw0 = wr[0], tw1 = wr[1], tw2 = wr[2];
#pragma unroll
          for (int i = 0; i < 8; ++i) {
            accs[cc][i] += tw0 * v10[i];     // sequential v_fmac, R8 order
            accs[cc][i] += tw1 * v10[i + 1];
            accs[cc][i] += tw2 * v10[i + 2];
          }
        }
      }
      int wic = (2 * cg + p) & 3;
      int clb = cg >> 1;
#pragma unroll
      for (int k = 0; k < 8; ++k) {
        int pxl = (k + oct) & 7;
        int px = oct * 8 + pxl;
        Xs[px * 64 + (((clb ^ pxl) & 15) << 2) + wic] = pk2(accs[0][pxl], accs[1][pxl]);
      }
    }
    __syncthreads();

    f32x16 acc0 = {}, acc1 = {};
    gemm_core(Xs, Wtp, lane, wid, acc0, acc1);

    int obase = wid * 32 + 4 * hi;
#pragma unroll
    for (int r = 0; r < 16; ++r) {
      int o = obase + (r & 3) + 8 * (r >> 2);
      float bb = cb[o];
      const float* rp = X + (b * C_ + o) * HW_ + h * W_ + w0;
      acc0[r] += bb + rp[lr];
      acc1[r] += bb + rp[32 + lr];
    }
    {
      float s0 = 0, s1 = 0, q0 = 0, q1 = 0;
#pragma unroll
      for (int r = 0; r < 16; ++r) {
        s0 += acc0[r]; q0 += acc0[r] * acc0[r];
        s1 += acc1[r]; q1 += acc1[r] * acc1[r];
      }
      s0 += __shfl_xor(s0, 32); q0 += __shfl_xor(q0, 32);
      s1 += __shfl_xor(s1, 32); q1 += __shfl_xor(q1, 32);
      if (hi == 0) {
        red[wid * 64 + lr] = s0;       red[wid * 64 + 32 + lr] = s1;
        red[256 + wid * 64 + lr] = q0; red[256 + wid * 64 + 32 + lr] = q1;
      }
      __syncthreads();
      if (t < 64) {
        float ss = red[t] + red[64 + t] + red[128 + t] + red[192 + t];
        float qq = red[256 + t] + red[320 + t] + red[384 + t] + red[448 + t];
        float mu = ss * (1.0f / 128.0f);
        float var = qq * (1.0f / 128.0f) - mu * mu;   // biased
        red[512 + t] = mu;
        red[576 + t] = rsqrtf(var + 1e-6f);
      }
      __syncthreads();
      float mu0 = red[512 + lr], rs0 = red[576 + lr];
      float mu1 = red[544 + lr], rs1 = red[608 + lr];
#pragma unroll
      for (int r = 0; r < 16; ++r) {
        int o = obase + (r & 3) + 8 * (r >> 2);
        float lw = lnw[o], lb2 = lnb[o];
        acc0[r] = lw * ((acc0[r] - mu0) * rs0) + lb2;
        acc1[r] = lw * ((acc1[r] - mu1) * rs1) + lb2;
      }
    }
#pragma unroll
    for (int r = 0; r < 16; r += 2) {
      int o = obase + (r & 3) + 8 * (r >> 2);
      unsigned* orow = O + (b * 64 + (o >> 1)) * HW_ + h * W_ + w0;
      orow[lr] = pk2(acc0[r], acc0[r + 1]);
      orow[32 + lr] = pk2(acc1[r], acc1[r + 1]);
    }
  } else {
    // ======== V projection path (R14 k_qv ty>=2 verbatim) ========
    const float* S = (ty == 2) ? X0 : X1;
    const ushort_t* Wb = (ty == 2) ? WV0 : WV1;
    int ch8 = t >> 4, pxq = t & 15;
    int c0 = ch8 * 8, wb2 = w0 + pxq * 4;
    float vv[8][4];
#pragma unroll
    for (int cc = 0; cc < 8; ++cc) {
      int c = c0 + cc;
      int g = c >> 4;
      const float* rowp = S + (b * C_ + c) * HW_ + h * W_;
      if (g >= 4) {
        float4 a = *(const float4*)(rowp + wb2);
        vv[cc][0] = a.x; vv[cc][1] = a.y; vv[cc][2] = a.z; vv[cc][3] = a.w;
      } else if (g >= 2) {
        int hh = h + (g == 2 ? 1 : -1);
        if (hh >= 0 && hh < H_) {
          float4 a = *(const float4*)(S + (b * C_ + c) * HW_ + hh * W_ + wb2);
          vv[cc][0] = a.x; vv[cc][1] = a.y; vv[cc][2] = a.z; vv[cc][3] = a.w;
        } else { vv[cc][0] = vv[cc][1] = vv[cc][2] = vv[cc][3] = 0.f; }
      } else if (g == 0) {       // w+1 shift
        float4 a = *(const float4*)(rowp + wb2);
        float x4 = (wb2 + 4 < W_) ? rowp[wb2 + 4] : 0.f;
        vv[cc][0] = a.y; vv[cc][1] = a.z; vv[cc][2] = a.w; vv[cc][3] = x4;
      } else {                    // w-1 shift
        float4 a = *(const float4*)(rowp + wb2);
        float xm = (wb2 > 0) ? rowp[wb2 - 1] : 0.f;
        vv[cc][0] = xm; vv[cc][1] = a.x; vv[cc][2] = a.y; vv[cc][3] = a.z;
      }
    }
#pragma unroll
    for (int i = 0; i < 4; ++i) {
      int px = pxq * 4 + i;
      int cl = ch8 ^ (px & 7);
      *(uint4*)&Xs[px * 64 + cl * 4] =
          make_uint4(pk2(vv[0][i], vv[1][i]), pk2(vv[2][i], vv[3][i]),
                     pk2(vv[4][i], vv[5][i]), pk2(vv[6][i], vv[7][i]));
    }
    __syncthreads();

    f32x16 acc0 = {}, acc1 = {};
    gemm_core(Xs, Wb, lane, wid, acc0, acc1);

    int obase = wid * 32 + 4 * hi;
    unsigned* O = (ty == 2) ? V0 : V1;
#pragma unroll
    for (int r = 0; r < 16; r += 2) {
      int o = obase + (r & 3) + 8 * (r >> 2);                 // even
      unsigned* orow = O + (b * 64 + (o >> 1)) * HW_ + h * W_ + w0;
      orow[lr] = pk2(acc0[r], acc0[r + 1]);
      orow[32 + lr] = pk2(acc1[r], acc1[r + 1]);
    }
  }
}

// ---------------- k_q: Q projections only (R14 k_qv ty<2 verbatim) ----------------
__global__ __launch_bounds__(256) void k_q(
    const unsigned* __restrict__ B0, const unsigned* __restrict__ B1,
    const ushort_t* __restrict__ WQ0, const ushort_t* __restrict__ WQ1,
    unsigned* __restrict__ Q0, unsigned* __restrict__ Q1) {
  __shared__ __align__(16) unsigned Xs[64 * 64];
  int ty = blockIdx.y;                // 0 QL, 1 QR
  int bid = xcd_remap(blockIdx.x);
  int b = bid >> 9, h = (bid >> 2) & 127, w0 = (bid & 3) << 6;
  int t = threadIdx.x;
  int lane = t & 63, wid = t >> 6, hi = lane >> 5, lr = lane & 31;
  const ushort_t* Wb = ty ? WQ1 : WQ0;
  const unsigned* S = ty ? B1 : B0;

#pragma unroll
  for (int uu = 0; uu < 4; ++uu) {
    int unit = uu * 256 + t;
    int c2u = unit >> 4, pxq = unit & 15;
    int wb2 = w0 + pxq * 4;
    int g = c2u >> 3;
    unsigned v[4];
    const unsigned* rowp = S + (b * 64 + c2u) * HW_ + h * W_;
    if (g >= 4) {
      uint4 a = *(const uint4*)(rowp + wb2);
      v[0] = a.x; v[1] = a.y; v[2] = a.z; v[3] = a.w;
    } else if (g >= 2) {
      int hh = h + (g == 2 ? 1 : -1);
      if (hh >= 0 && hh < H_) {
        uint4 a = *(const uint4*)(S + (b * 64 + c2u) * HW_ + hh * W_ + wb2);
        v[0] = a.x; v[1] = a.y; v[2] = a.z; v[3] = a.w;
      } else { v[0] = v[1] = v[2] = v[3] = 0u; }
    } else {
      int d = (g == 0) ? 1 : -1;
#pragma unroll
      for (int i = 0; i < 4; ++i) {
        int ww = wb2 + i + d;
        v[i] = (ww >= 0 && ww < W_) ? rowp[ww] : 0u;
      }
    }
#pragma unroll
    for (int i = 0; i < 4; ++i) {
      int px = pxq * 4 + i;
      Xs[px * 64 + (((c2u >> 2) ^ (px & 7)) << 2) + (c2u & 3)] = v[i];
    }
  }
  __syncthreads();

  f32x16 acc0 = {}, acc1 = {};
  gemm_core(Xs, Wb, lane, wid, acc0, acc1);

  int obase = wid * 32 + 4 * hi;
  unsigned* O = ty ? Q1 : Q0;
#pragma unroll
  for (int r = 0; r < 16; r += 2) {
    int o = obase + (r & 3) + 8 * (r >> 2);                 // even
    unsigned* orow = O + b * CHW_ + o * HW_ + h * W_ + w0;  // even-slot strided
    orow[lr] = pk2(acc0[r], acc0[r + 1]);
    orow[32 + lr] = pk2(acc1[r], acc1[r + 1]);
  }
}

// ============ MFMA attention (R10 fused; T14 vL prefetch) — UNCHANGED ============
DEVI bf16x8 ldfrag(const unsigned* A, int r, int cl) {
  int clp = cl ^ ((r >> 1) & 3);
  uint4 v = *(const uint4*)(A + r * 16 + clp * 4);
  return __builtin_bit_cast(bf16x8, v);
}
DEVI bf16x8 vfrag(const unsigned* Vt, int c, int ktg, int hi) {
  int jc = 2 * ktg + hi;
  int jcp = jc ^ (c & 7);
  uint4 v = *(const uint4*)(Vt + c * 128 + jcp * 4);
  return __builtin_bit_cast(bf16x8, v);
}
DEVI void stageQ16(const unsigned* __restrict__ G, unsigned* A, int t) {
  unsigned r[16];
#pragma unroll
  for (int c2 = 0; c2 < 16; ++c2) r[c2] = G[(2 * c2) * HW_ + t];
  int sw = (t >> 1) & 3;
#pragma unroll
  for (int cl = 0; cl < 4; ++cl) {
    int clp = cl ^ sw;
    *(uint4*)(A + t * 16 + clp * 4) =
        make_uint4(r[cl * 4], r[cl * 4 + 1], r[cl * 4 + 2], r[cl * 4 + 3]);
  }
}
DEVI void stageVt_wr(const unsigned* vbuf, unsigned* Vt, int t) {
  ushort_t* V16 = (ushort_t*)Vt;
#pragma unroll
  for (int c2 = 0; c2 < 16; ++c2) {
    unsigned u = vbuf[c2];
#pragma unroll
    for (int e = 0; e < 2; ++e) {
      int c = 2 * c2 + e;
      int w16 = (c * 128 + (((t >> 3) ^ (c & 7)) << 2) + ((t >> 1) & 3)) * 2 + (t & 1);
      V16[w16] = (ushort_t)(e ? (u >> 16) : (u & 0xffffu));
    }
  }
}
DEVI void stageVt(const unsigned* __restrict__ G, unsigned* Vt, int t) {
  unsigned vbuf[16];
#pragma unroll
  for (int c2 = 0; c2 < 16; ++c2) vbuf[c2] = G[c2 * HW_ + t];
  stageVt_wr(vbuf, Vt, t);
}
DEVI void psv_comp(const unsigned* Vt, float* psv, int t) {
  int jt = t >> 5, c = t & 31;
  float s = 0.f;
#pragma unroll
  for (int q = 0; q < 4; ++q) {
    int jcp = (4 * jt + q) ^ (c & 7);
    s += sum8(*(const uint4*)(Vt + c * 128 + jcp * 4));
  }
  psv[jt * 32 + c] = s;
}

template <int DIR>
DEVI void attn_pass(const unsigned* Ql_, const unsigned* Qk_, const unsigned* Vt,
                    const float* psv, float* emr, unsigned* __restrict__ outG,
                    int wid, int lane) {
  int hi = lane >> 5, cq = lane & 31;
#pragma unroll
  for (int s = 0; s < 2; ++s) {
    int qt = 2 * wid + s;
    int q = qt * 32 + cq;
    int jt0 = DIR ? qt : (qt >= 3 ? qt - 3 : 0);
    int jt1 = DIR ? (qt <= 4 ? qt + 3 : 7) : qt;
    int nt = jt1 - jt0 + 1;                      // wave-uniform
    bf16x8 bq0 = ldfrag(Ql_, q, hi);
    bf16x8 bq1 = ldfrag(Ql_, q, hi + 2);
    f32x16 S[4];
#pragma unroll
    for (int ji = 0; ji < 4; ++ji) {
      if (ji < nt) {
        int jt = jt0 + ji;
        f32x16 d = {};
        d = __builtin_amdgcn_mfma_f32_32x32x16_bf16(
            ldfrag(Qk_, jt * 32 + cq, hi), bq0, d, 0, 0, 0);
        d = __builtin_amdgcn_mfma_f32_32x32x16_bf16(
            ldfrag(Qk_, jt * 32 + cq, hi + 2), bq1, d, 0, 0, 0);
        S[ji] = d;
      }
    }
    float m = 0.f;
#pragma unroll
    for (int ji = 0; ji < 4; ++ji) if (ji < nt) {
      int jb = (jt0 + ji) * 32 + 4 * hi;
#pragma unroll
      for (int r = 0; r < 16; ++r) {
        int j = jb + (r & 3) + 8 * (r >> 2);
        bool act = DIR ? (j >= q && j <= q + MD_) : (j <= q && j >= q - MD_);
        float v = act ? S[ji][r] : 0.f;
        S[ji][r] = v;
        m = fmaxf(m, v);
      }
    }
    m = fmaxf(m, __shfl_xor(m, 32));
    float em_ = __expf(-m);
    float lsum = 0.f;
#pragma unroll
    for (int ji = 0; ji < 4; ++ji) if (ji < nt) {
#pragma unroll
      for (int r = 0; r < 16; ++r) {
        float e = __expf(S[ji][r] - m);
        S[ji][r] = e;
        lsum += e;
      }
    }
    lsum += __shfl_xor(lsum, 32);
    lsum += (float)((8 - nt) * 32) * em_;
    float rl = 1.f / lsum;
    if (hi == 0) { emr[qt * 32 + cq] = em_; emr[256 + qt * 32 + cq] = rl; }
    f32x16 acc = {};
#pragma unroll
    for (int ji = 0; ji < 4; ++ji) if (ji < nt) {
      int jt = jt0 + ji;
      unsigned x[8], ox[8];
#pragma unroll
      for (int w2 = 0; w2 < 8; ++w2) x[w2] = pk2(S[ji][2 * w2], S[ji][2 * w2 + 1]);
#pragma unroll
      for (int w2 = 0; w2 < 8; ++w2) ox[w2] = __shfl_xor(x[w2], 32);
#pragma unroll
      for (int hf = 0; hf < 2; ++hf) {
        unsigned w0 = hi ? ox[4 * hf + 2] : x[4 * hf + 0];
        unsigned w1 = hi ? ox[4 * hf + 3] : x[4 * hf + 1];
        unsigned w2_ = hi ? x[4 * hf + 2] : ox[4 * hf + 0];
        unsigned w3 = hi ? x[4 * hf + 3] : ox[4 * hf + 1];
        uint4 aw = make_uint4(w0, w1, w2_, w3);
        acc = __builtin_amdgcn_mfma_f32_32x32x16_bf16(
            __builtin_bit_cast(bf16x8, aw), vfrag(Vt, cq, 2 * jt + hf, hi),
            acc, 0, 0, 0);
      }
    }
    float Rv = 0.f;
#pragma unroll
    for (int jt = 0; jt < 8; ++jt)
      if (jt < jt0 || jt > jt1) Rv += psv[jt * 32 + cq];
    // out: bf16 px-paired [c][HW/2]; rows qr0 (even), qr0+1 are IN-LANE
#pragma unroll
    for (int r = 0; r < 16; r += 2) {
      int qr0 = (r & 3) + 8 * (r >> 2) + 4 * hi;               // even
      float v0 = (acc[r] + emr[qt * 32 + qr0] * Rv) * emr[256 + qt * 32 + qr0];
      float v1 = (acc[r + 1] + emr[qt * 32 + qr0 + 1] * Rv) * emr[256 + qt * 32 + qr0 + 1];
      outG[cq * (HW_ / 2) + ((qt * 32 + qr0) >> 1)] = pk2(v0, v1);
    }
  }
}

__global__ __launch_bounds__(256) void k_attn(
    const unsigned* __restrict__ qL, const unsigned* __restrict__ qR,
    const unsigned* __restrict__ vL, const unsigned* __restrict__ vR,
    unsigned* __restrict__ wL, unsigned* __restrict__ wR) {
  __shared__ __align__(16) unsigned Ql[4096];
  __shared__ __align__(16) unsigned Qr[4096];
  __shared__ __align__(16) unsigned Vt[4096];
  __shared__ float psv[256];
  __shared__ float emr[512];
  int t = threadIdx.x;
  int bid = blockIdx.x;
  int b = bid >> 9, k4 = (bid >> 7) & 3, h = bid & 127;
  int qoff = b * CHW_ + (k4 * CG_) * HW_ + h * W_;             // even-slot strided base
  int voff = (b * 64 + k4 * 16) * HW_ + h * W_;                // compact pair base (V in)
  int woff = (b * C_ + k4 * CG_) * (HW_ / 2) + h * (W_ / 2);   // px-paired base (warp out)
  stageQ16(qL + qoff, Ql, t);
  stageQ16(qR + qoff, Qr, t);
  stageVt(vR + voff, Vt, t);
  __syncthreads();
  psv_comp(Vt, psv, t);
  __syncthreads();
  int wid = t >> 6, lane = t & 63;
  // T14: issue vL global loads NOW; latency hides under pass L.
  unsigned vbuf[16];
  {
    const unsigned* G = vL + voff;
#pragma unroll
    for (int c2 = 0; c2 < 16; ++c2) vbuf[c2] = G[c2 * HW_ + t];
  }
  attn_pass<0>(Ql, Qr, Vt, psv, emr, wL + woff, wid, lane);
  __syncthreads();
  stageVt_wr(vbuf, Vt, t);      // LDS-write half only
  __syncthreads();
  psv_comp(Vt, psv, t);
  __syncthreads();
  attn_pass<1>(Qr, Ql, Vt, psv, emr, wR + woff, wid, lane);
}

// ---------------- k_fin: final conv + residual -> f32 out — UNCHANGED ----------------
__global__ __launch_bounds__(256) void k_fin(
    const unsigned* __restrict__ W0, const unsigned* __restrict__ W1,
    const float* __restrict__ X0, const float* __restrict__ X1,
    const ushort_t* __restrict__ Wb,
    float* __restrict__ O0, float* __restrict__ O1) {
  __shared__ __align__(16) unsigned Xs[64 * 64];
  int side = blockIdx.y;
  const unsigned* Wsrc = side ? W1 : W0;
  const float* R = side ? X1 : X0;
  float* O = side ? O1 : O0;
  int bid = blockIdx.x;
  int b = bid >> 9, h = (bid >> 2) & 127, w0 = (bid & 3) << 6;
  int t = threadIdx.x;
  int lane = t & 63, wid = t >> 6, hi = lane >> 5, lr = lane & 31;
#pragma unroll
  for (int uu = 0; uu < 8; ++uu) {
    int unit = uu * 256 + t;
    int cp = unit >> 5;             // channel-pair 0..63
    int jp = unit & 31;             // px-pair 0..31
    const unsigned* base = Wsrc + h * (W_ / 2) + (w0 >> 1) + jp;
    unsigned lo = base[(b * C_ + 2 * cp) * (HW_ / 2)];       // ch 2cp:   px 2jp, 2jp+1
    unsigned hi2 = base[(b * C_ + 2 * cp + 1) * (HW_ / 2)];  // ch 2cp+1: px 2jp, 2jp+1
    unsigned w0p = (lo & 0xffffu) | (hi2 << 16);             // px 2jp
    unsigned w1p = (lo >> 16) | (hi2 & 0xffff0000u);         // px 2jp+1
    int px0 = 2 * jp, px1 = 2 * jp + 1;
    Xs[px0 * 64 + (((cp >> 2) ^ (px0 & 7)) << 2) + (cp & 3)] = w0p;
    Xs[px1 * 64 + (((cp >> 2) ^ (px1 & 7)) << 2) + (cp & 3)] = w1p;
  }
  __syncthreads();
  f32x16 acc0 = {}, acc1 = {};
  gemm_core(Xs, Wb, lane, wid, acc0, acc1);
  int obase = wid * 32 + 4 * hi;
#pragma unroll
  for (int r = 0; r < 16; ++r) {
    int o = obase + (r & 3) + 8 * (r >> 2);
    const float* rp = R + (b * C_ + o) * HW_ + h * W_ + w0;
    float* op = O + (b * C_ + o) * HW_ + h * W_ + w0;
    op[lr] = acc0[r] + rp[lr];
    op[32 + lr] = acc1[r] + rp[32 + lr];
  }
}

// ---------------- launch ----------------
extern "C" void kernel_launch(void* const* d_in, const int* in_sizes, int n_in,
                              void* d_out, int out_size, void* d_ws, size_t ws_size,
                              hipStream_t stream) {
  const float* xl0    = (const float*)d_in[0];
  const float* xr0    = (const float*)d_in[1];
  const float* ln_l_w = (const float*)d_in[2];
  const float* ln_l_b = (const float*)d_in[3];
  const float* ln_r_w = (const float*)d_in[4];
  const float* ln_r_b = (const float*)d_in[5];
  const float* feaL_w = (const float*)d_in[6];
  const float* feaR_w = (const float*)d_in[7];
  const float* to_l_w = (const float*)d_in[8];
  const float* to_r_w = (const float*)d_in[9];
  const float* td_w   = (const float*)d_in[10];
  const float* td_b   = (const float*)d_in[11];
  const float* tp_w   = (const float*)d_in[12];
  const float* tp_b   = (const float*)d_in[13];
  const float* out_w  = (const float*)d_in[14];

  float* o0 = (float*)d_out;                 // final left (Q scratch first)
  float* o1 = o0 + TEN_;                     // final right
  unsigned* qL = (unsigned*)d_out;           // even-slot strided pairs in o0 region
  unsigned* qR = qL + TEN_;                  // in o1 region
  unsigned* bL = (unsigned*)d_ws;            // x_left bf16 pairs; later warpL (px-paired)
  unsigned* bR = bL + P16_;                  // x_right; later warpR
  unsigned* vL = bR + P16_;                  // V bf16 pairs (compact)
  unsigned* vR = vL + P16_;
  ushort_t* wb = (ushort_t*)(vR + P16_);
  ushort_t* wb_feaL = wb + 0 * 16384;
  ushort_t* wb_feaR = wb + 1 * 16384;
  ushort_t* wb_tol  = wb + 2 * 16384;
  ushort_t* wb_tor  = wb + 3 * 16384;
  ushort_t* wb_tp   = wb + 4 * 16384;
  ushort_t* wb_out  = wb + 5 * 16384;

  WbPack pw;
  pw.s[0] = feaL_w; pw.s[1] = feaR_w; pw.s[2] = to_l_w;
  pw.s[3] = to_r_w; pw.s[4] = tp_w;   pw.s[5] = out_w;
  pw.d[0] = wb_feaL; pw.d[1] = wb_feaR; pw.d[2] = wb_tol;
  pw.d[3] = wb_tor;  pw.d[4] = wb_tp;   pw.d[5] = wb_out;
  k_wb<<<dim3(64, 6), 256, 0, stream>>>(pw);

  // transition + V projections in ONE dispatch (independent work overlapped)
  k_tv<<<dim3(1024, 4), 256, 0, stream>>>(
      xl0, xr0, wb_tp, wb_feaL, wb_feaR, td_w, td_b, tp_b,
      ln_l_w, ln_l_b, ln_r_w, ln_r_b, bL, bR, vL, vR);

  // Q projections (shifted x_left/right)
  k_q<<<dim3(1024, 2), 256, 0, stream>>>(bL, bR, wb_tol, wb_tor, qL, qR);

  // MFMA attention (fused 2-pass, T14 vL prefetch) -> bf16 px-paired warp
  k_attn<<<1024, 256, 0, stream>>>(qL, qR, vL, vR, bL, bR);

  // final conv + residual -> f32 outputs (overwrites Q scratch in d_out)
  k_fin<<<dim3(1024, 2), 256, 0, stream>>>(
      bL, bR, xl0, xr0, wb_out, o0, o1);
}